// Round 2
// 833.903 us; speedup vs baseline: 1.1337x; 1.1337x over previous
//
#include <hip/hip_runtime.h>
#include <hip/hip_bf16.h>
#include <math.h>
#include <stdint.h>

using bf16 = __hip_bfloat16;
typedef __attribute__((ext_vector_type(4))) float f32x4;
typedef __attribute__((ext_vector_type(8))) short s16x8;

#define MFMA16(a, b, c) __builtin_amdgcn_mfma_f32_16x16x32_bf16(a, b, c, 0, 0, 0)

__device__ __forceinline__ void gload_lds16(const void* g, void* l) {
    __builtin_amdgcn_global_load_lds(
        (const __attribute__((address_space(1))) void*)g,
        (__attribute__((address_space(3))) void*)l, 16, 0, 0);
}

// ---------------- fp32 -> bf16 straight convert (8 elems/thread) ----------------
struct alignas(16) bf16x8s { bf16 v[8]; };

__global__ void cvt_f32_bf16(const float* __restrict__ in, bf16* __restrict__ out, long n) {
    long i = ((long)blockIdx.x * 256 + threadIdx.x) * 8;
    if (i >= n) return;
    float4 a = *(const float4*)(in + i);
    float4 b = *(const float4*)(in + i + 4);
    bf16x8s r;
    r.v[0] = __float2bfloat16(a.x); r.v[1] = __float2bfloat16(a.y);
    r.v[2] = __float2bfloat16(a.z); r.v[3] = __float2bfloat16(a.w);
    r.v[4] = __float2bfloat16(b.x); r.v[5] = __float2bfloat16(b.y);
    r.v[6] = __float2bfloat16(b.z); r.v[7] = __float2bfloat16(b.w);
    *(bf16x8s*)(out + i) = r;
}

// ---------------- fp32 [K][N] -> bf16 [N][K] transpose-convert ----------------
__global__ void transpose_cvt(const float* __restrict__ W, bf16* __restrict__ Wt, int K, int N) {
    __shared__ bf16 t[32][33];
    int tx = threadIdx.x & 31, ty = threadIdx.x >> 5;
    int n0 = blockIdx.x * 32, k0 = blockIdx.y * 32;
    #pragma unroll
    for (int r = ty; r < 32; r += 8)
        t[r][tx] = __float2bfloat16(W[(size_t)(k0 + r) * N + n0 + tx]);
    __syncthreads();
    #pragma unroll
    for (int r = ty; r < 32; r += 8)
        Wt[(size_t)(n0 + r) * K + k0 + tx] = t[tx][r];
}

// ---------------- 256x128 ring-3 deep-pipelined GEMM ----------------
// C[M,N] = A[M,K] * Bt[N,K]^T, bf16 in, fp32 acc.
// 512 thr = 8 waves (4M x 2N), per-wave 64x64 output, BK=64, 2 phases/K-tile.
// LDS = STATIC ring of 3 K-tile slots (48 KB = A 32 KB + B 16 KB) = 144 KiB.
// (Static allocation: no hipFuncSetAttribute / dynamic-LDS launch inside the
// graph-captured kernel_launch — that host-API path is the R1 failure suspect.)
// XOR swizzle: 16B block index ^= (row & 7); written via pre-swizzled GLOBAL
// source with LINEAR global_load_lds dest (both-sides rule), read with same XOR.
// Stage tile t+2 during tile t (slot free since end of t-1 -> WAR-safe by
// barrier order); counted s_waitcnt vmcnt(6) at tile boundaries (never 0 until
// the final two boundaries). Raw s_barrier only - no __syncthreads drain.
// EPI 0: bf16 store. EPI 1: bias+gelu -> bf16. EPI 3: fp32 split-K partial.
// REQUIRES: M%256==0, N%128==0, (K/SPLITK)%64==0, K/SPLITK>=128,
//           gridDim.x*gridDim.y % 8 == 0.
#define GEMM_LDS (3 * 49152)

template <int EPI, int SPLITK>
__global__ __launch_bounds__(512) void gemm_pipe(
    const bf16* __restrict__ A, const bf16* __restrict__ Bt,
    void* __restrict__ C, const float* __restrict__ bias,
    const float* __restrict__ resid, int M, int N, int K)
{
    __shared__ __align__(16) char smem[GEMM_LDS];
    const int tid = threadIdx.x;
    const int wid = tid >> 6, lane = tid & 63;
    const int quad = lane >> 4, l16 = lane & 15;

    // XCD-aware bijective block swizzle (nwg % 8 == 0 guaranteed by launcher)
    const int nx = gridDim.x;
    const int nwg = nx * gridDim.y;
    int lin = blockIdx.y * nx + blockIdx.x;
    const int cpx = nwg >> 3;
    lin = (lin & 7) * cpx + (lin >> 3);
    const int bm = (lin % nx) * 256, bn = (lin / nx) * 128;

    const int wrow = (wid >> 1) * 64;      // wave M offset: 0,64,128,192
    const int wcol = (wid & 1) * 64;       // wave N offset: 0,64
    const int KH = K / SPLITK;
    const int kbeg = blockIdx.z * KH;
    const int NT = KH / 64;

    // Staging (pre-swizzled source): thread owns 16B at linear LDS byte
    // soff + c*8192; row = (soff>>7)+c*64, 16B-block pb = (soff>>4)&7;
    // global block = pb ^ (row&7). row&7 is c-invariant (c*64 % 8 == 0).
    const int soff = tid * 16;
    const int ar0 = soff >> 7;                              // 0..63
    const int agc = ((((soff >> 4) & 7) ^ (ar0 & 7)) << 3); // bf16 col offset
    const bf16* Ab = A + (size_t)(bm + ar0) * K + kbeg + agc;
    const bf16* Bb = Bt + (size_t)(bn + ar0) * K + kbeg + agc;

    // Fragment read offsets (bf16 elems): row*64 + ((blk ^ (l16&7))<<3);
    // row&7 == l16&7 since wrow, mt*16 are multiples of 8 rows (mod 8 == 0).
    const int asw = l16 & 7;
    const int ko0 = (quad ^ asw) << 3;          // ks=0 blocks 0..3
    const int ko1 = ((4 + quad) ^ asw) << 3;    // ks=1 blocks 4..7
    const int arb = (wrow + l16) * 64;
    const int brb = (wcol + l16) * 64;

    f32x4 acc[4][4] = {};

#define STAGE_A(tt, dst) { \
    _Pragma("unroll") \
    for (int c = 0; c < 4; ++c) \
        gload_lds16(Ab + (size_t)(c * 64) * K + (tt) * 64, \
                    (dst) + wid * 1024 + c * 8192); }
#define STAGE_B(tt, dst) { \
    _Pragma("unroll") \
    for (int c = 0; c < 2; ++c) \
        gload_lds16(Bb + (size_t)(c * 64) * K + (tt) * 64, \
                    (dst) + wid * 1024 + c * 8192); }

    // prologue: tiles 0,1 -> slots 0,1 (12 loads/wave); retire tile 0 (oldest 6)
    STAGE_A(0, smem);
    STAGE_B(0, smem + 32768);
    STAGE_A(1, smem + 49152);
    STAGE_B(1, smem + 49152 + 32768);
    asm volatile("s_waitcnt vmcnt(6)\ns_barrier" ::: "memory");

    int st = 0;
    for (int t = 0; t < NT; ++t) {
        char* base = smem + st * 49152;
        const bf16* As = (const bf16*)base;
        const bf16* Bs = (const bf16*)(base + 32768);
        int s2 = st + 2; if (s2 >= 3) s2 -= 3;
        char* pre = smem + s2 * 49152;
        const bool doPre = (t + 2 < NT);

        // ---- phase 1 (ks = 0) ----
        s16x8 a0[4], b0[4];
        #pragma unroll
        for (int mt = 0; mt < 4; ++mt)
            a0[mt] = *(const s16x8*)(As + arb + mt * 1024 + ko0);
        #pragma unroll
        for (int nt = 0; nt < 4; ++nt)
            b0[nt] = *(const s16x8*)(Bs + brb + nt * 1024 + ko0);
        if (doPre) STAGE_A(t + 2, pre);
        __builtin_amdgcn_s_barrier();
        __builtin_amdgcn_s_setprio(1);
        #pragma unroll
        for (int mt = 0; mt < 4; ++mt)
            #pragma unroll
            for (int nt = 0; nt < 4; ++nt)
                acc[mt][nt] = MFMA16(a0[mt], b0[nt], acc[mt][nt]);
        __builtin_amdgcn_s_setprio(0);
        __builtin_amdgcn_s_barrier();

        // ---- phase 2 (ks = 1) ----
        s16x8 a1[4], b1[4];
        #pragma unroll
        for (int mt = 0; mt < 4; ++mt)
            a1[mt] = *(const s16x8*)(As + arb + mt * 1024 + ko1);
        #pragma unroll
        for (int nt = 0; nt < 4; ++nt)
            b1[nt] = *(const s16x8*)(Bs + brb + nt * 1024 + ko1);
        if (doPre) STAGE_B(t + 2, pre + 32768);
        __builtin_amdgcn_s_barrier();
        __builtin_amdgcn_s_setprio(1);
        #pragma unroll
        for (int mt = 0; mt < 4; ++mt)
            #pragma unroll
            for (int nt = 0; nt < 4; ++nt)
                acc[mt][nt] = MFMA16(a1[mt], b1[nt], acc[mt][nt]);
        __builtin_amdgcn_s_setprio(0);
        // tile boundary: tile t+1's 6 loads (issued last iter) must be retired;
        // this iter's 6 (tile t+2) may stay in flight. Tail (no new issues):
        // the most recent 6 ARE tile NT-1's -> drain.
        if (doPre) { asm volatile("s_waitcnt vmcnt(6)\ns_barrier" ::: "memory"); }
        else       { asm volatile("s_waitcnt vmcnt(0)\ns_barrier" ::: "memory"); }
        st = st + 1 == 3 ? 0 : st + 1;
    }
#undef STAGE_A
#undef STAGE_B

    float* Cp = (float*)C;
    if (EPI == 3) Cp += (size_t)blockIdx.z * M * N;

    #pragma unroll
    for (int mt = 0; mt < 4; ++mt) {
        #pragma unroll
        for (int nt = 0; nt < 4; ++nt) {
            #pragma unroll
            for (int r = 0; r < 4; ++r) {
                int row = bm + wrow + mt * 16 + quad * 4 + r;
                int col = bn + wcol + nt * 16 + l16;
                float v = acc[mt][nt][r];
                if (EPI == 0) {
                    ((bf16*)C)[(size_t)row * N + col] = __float2bfloat16(v);
                } else if (EPI == 1) {
                    float xx = v + bias[col];
                    float g = 0.5f * xx * (1.0f + erff(xx * 0.7071067811865475f));
                    ((bf16*)C)[(size_t)row * N + col] = __float2bfloat16(g);
                } else if (EPI == 2) {
                    ((float*)C)[(size_t)row * N + col] =
                        v + bias[col] + resid[(size_t)row * N + col];
                } else {
                    Cp[(size_t)row * N + col] = v;
                }
            }
        }
    }
}

// ---------------- RoPE (reference indexes sin/cos by BATCH, not position) --------
__global__ void rope_kernel(const bf16* __restrict__ in, bf16* __restrict__ out,
                            const float* __restrict__ sn, const float* __restrict__ cs,
                            int S, int D, int instride) {
    int row = blockIdx.x;
    int pos = row / S;                 // batch index — matches reference broadcast
    const int half = D >> 1;
    const bf16* r = in + (size_t)row * instride;
    bf16* o = out + (size_t)row * D;
    for (int j = threadIdx.x; j < half; j += 256) {
        uint32_t pr = *(const uint32_t*)(r + 2 * j);
        float x1 = __uint_as_float(pr << 16);
        float x2 = __uint_as_float(pr & 0xffff0000u);
        float c = cs[(size_t)pos * half + j], s = sn[(size_t)pos * half + j];
        o[j]        = __float2bfloat16(x1 * c - x2 * s);
        o[half + j] = __float2bfloat16(x1 * s + x2 * c);
    }
}

// ---------------- V transpose per head: v[b,s,h,d] (strided) -> vt[bh, d, s] -----
__global__ void vtrans_kernel(const bf16* __restrict__ v, bf16* __restrict__ vt,
                              int S, int D, int H, int instride) {
    __shared__ bf16 t[32][33];
    int bh = blockIdx.z, b = bh >> 4, h = bh & 15;
    int s0 = blockIdx.x * 32, d0 = blockIdx.y * 32;
    int tx = threadIdx.x & 31, ty = threadIdx.x >> 5;
    #pragma unroll
    for (int r = ty; r < 32; r += 8)
        t[r][tx] = v[(size_t)(b * S + s0 + r) * instride + h * 128 + d0 + tx];
    __syncthreads();
    #pragma unroll
    for (int r = ty; r < 32; r += 8)
        vt[((size_t)bh * 128 + d0 + r) * S + s0 + tx] = t[tx][r];
}

// ---------------- Flash attention, transposed-score form ----------------
__global__ __launch_bounds__(256, 4) void attn_kernel(
    const bf16* __restrict__ q, const bf16* __restrict__ k, const bf16* __restrict__ vt,
    float* __restrict__ o, int S, int D, int H)
{
    __shared__ __align__(16) char smem[40960];
    bf16* Ks = (bf16*)smem;                 // [64 k][128 d], 16B-block XOR swizzle
    bf16* Vs = (bf16*)(smem + 16384);       // [128 d][64 k], swizzled
    bf16* Ps = (bf16*)(smem + 32768);       // per-wave [16 q][64 k], swizzled

    const int tid = threadIdx.x, wid = tid >> 6, lane = tid & 63;
    const int quad = lane >> 4, l16 = lane & 15;
    const int bh = blockIdx.x, b = bh >> 4, h = bh & 15;
    const int qt = gridDim.y - 1 - blockIdx.y;     // big tiles dispatched first
    const float scale = 0.08838834764831845f;      // 1/sqrt(128)

    s16x8 qf[4];
    const bf16* qrow = q + ((size_t)(b * S + qt * 64 + wid * 16 + l16)) * D + h * 128;
    #pragma unroll
    for (int ks = 0; ks < 4; ++ks)
        qf[ks] = *(const s16x8*)(qrow + ks * 32 + quad * 8);

    f32x4 oacc[8] = {};
    float mstate = -INFINITY, lstate = 0.f;

    const bf16* kb0 = k + (size_t)(b * S) * D + h * 128;
    const bf16* vb0 = vt + (size_t)bh * 128 * S;
    bf16* psw = Ps + wid * 16 * 64;
    const int sw = l16 & 7;
    const int nch = qt + 1;

    for (int kc = 0; kc < nch; ++kc) {
        __syncthreads();
        #pragma unroll
        for (int c = 0; c < 4; ++c) {
            int choff = (wid * 4 + c) << 10;
            int off = choff + lane * 16;
            int rk = off >> 8, bk = (off & 255) >> 4;
            gload_lds16(kb0 + (size_t)(kc * 64 + rk) * D + ((bk ^ (rk & 7)) << 3),
                        (char*)Ks + choff);
            int rv = off >> 7, bv = (off & 127) >> 4;
            gload_lds16(vb0 + (size_t)rv * S + kc * 64 + ((bv ^ (rv & 7)) << 3),
                        (char*)Vs + choff);
        }
        __syncthreads();

        f32x4 sacc[4] = {};
        #pragma unroll
        for (int mt = 0; mt < 4; ++mt) {
            #pragma unroll
            for (int ks = 0; ks < 4; ++ks) {
                s16x8 kf = *(const s16x8*)(Ks + (mt * 16 + l16) * 128 +
                                           (((ks * 4 + quad) ^ sw) << 3));
                sacc[mt] = MFMA16(kf, qf[ks], sacc[mt]);
            }
        }

        const bool need_mask = (kc == qt);
        #pragma unroll
        for (int mt = 0; mt < 4; ++mt)
            #pragma unroll
            for (int r = 0; r < 4; ++r) {
                float vv = sacc[mt][r] * scale;
                if (need_mask) {
                    int kl = mt * 16 + quad * 4 + r;
                    if (kl > wid * 16 + l16) vv = -INFINITY;
                }
                sacc[mt][r] = vv;
            }

        float mx = fmaxf(fmaxf(fmaxf(sacc[0][0], sacc[0][1]), fmaxf(sacc[0][2], sacc[0][3])),
                         fmaxf(fmaxf(sacc[1][0], sacc[1][1]), fmaxf(sacc[1][2], sacc[1][3])));
        mx = fmaxf(mx, fmaxf(fmaxf(fmaxf(sacc[2][0], sacc[2][1]), fmaxf(sacc[2][2], sacc[2][3])),
                             fmaxf(fmaxf(sacc[3][0], sacc[3][1]), fmaxf(sacc[3][2], sacc[3][3]))));
        mx = fmaxf(mx, __shfl_xor(mx, 16, 64));
        mx = fmaxf(mx, __shfl_xor(mx, 32, 64));
        float mnew = fmaxf(mstate, mx);
        float alpha = __expf(mstate - mnew);
        float rs = 0.f;
        #pragma unroll
        for (int mt = 0; mt < 4; ++mt)
            #pragma unroll
            for (int r = 0; r < 4; ++r) {
                float p = __expf(sacc[mt][r] - mnew);
                sacc[mt][r] = p;
                rs += p;
            }
        rs += __shfl_xor(rs, 16, 64);
        rs += __shfl_xor(rs, 32, 64);
        lstate = lstate * alpha + rs;
        mstate = mnew;
        #pragma unroll
        for (int mt = 0; mt < 8; ++mt)
            #pragma unroll
            for (int r = 0; r < 4; ++r) oacc[mt][r] *= alpha;

        #pragma unroll
        for (int mt = 0; mt < 4; ++mt)
            #pragma unroll
            for (int r = 0; r < 4; ++r) {
                int kl = mt * 16 + quad * 4 + r;
                psw[l16 * 64 + (((kl >> 3) ^ sw) << 3) + (kl & 7)] =
                    __float2bfloat16(sacc[mt][r]);
            }

        #pragma unroll
        for (int ks2 = 0; ks2 < 2; ++ks2) {
            s16x8 pf = *(const s16x8*)(psw + l16 * 64 + (((ks2 * 4 + quad) ^ sw) << 3));
            #pragma unroll
            for (int mt = 0; mt < 8; ++mt) {
                s16x8 vf = *(const s16x8*)(Vs + (mt * 16 + l16) * 64 +
                                           (((ks2 * 4 + quad) ^ sw) << 3));
                oacc[mt] = MFMA16(vf, pf, oacc[mt]);
            }
        }
    }

    float inv = 1.0f / lstate;
    __syncthreads();
    float* osw = (float*)smem + wid * 16 * 130;
    #pragma unroll
    for (int mt = 0; mt < 8; ++mt)
        #pragma unroll
        for (int r = 0; r < 4; ++r)
            osw[l16 * 130 + mt * 16 + quad * 4 + r] = oacc[mt][r] * inv;
    float* obase = o + (size_t)(b * S + qt * 64 + wid * 16) * D + h * 128;
    #pragma unroll
    for (int r16 = 0; r16 < 16; ++r16) {
        float2 val = *(const float2*)(osw + r16 * 130 + lane * 2);
        *(float2*)(obase + (size_t)r16 * D + lane * 2) = val;
    }
}

// ---------------- LayerNorm over D=2048: x = a (+b) (+c) (+bias), dual out ------
__global__ __launch_bounds__(256) void ln_kernel(
    const float* __restrict__ a, const float* __restrict__ b,
    const float* __restrict__ c, const float* __restrict__ bias,
    float* __restrict__ outf, bf16* __restrict__ outb, int D)
{
    int row = blockIdx.x;
    const float* pa = a + (size_t)row * D;
    const float* pb = b ? b + (size_t)row * D : nullptr;
    const float* pc = c ? c + (size_t)row * D : nullptr;
    float v[8];
    float sum = 0.f, sq = 0.f;
    #pragma unroll
    for (int u = 0; u < 8; ++u) {
        int j = threadIdx.x + u * 256;
        float x = pa[j];
        if (pb) x += pb[j];
        if (pc) x += pc[j];
        if (bias) x += bias[j];
        v[u] = x; sum += x; sq += x * x;
    }
    #pragma unroll
    for (int off = 32; off > 0; off >>= 1) {
        sum += __shfl_down(sum, off, 64);
        sq  += __shfl_down(sq,  off, 64);
    }
    __shared__ float red[8];
    int wid = threadIdx.x >> 6, lane = threadIdx.x & 63;
    if (lane == 0) { red[wid] = sum; red[4 + wid] = sq; }
    __syncthreads();
    sum = red[0] + red[1] + red[2] + red[3];
    sq  = red[4] + red[5] + red[6] + red[7];
    float mean = sum / D;
    float var = sq / D - mean * mean;
    float rstd = rsqrtf(fmaxf(var, 0.f) + 1e-5f);
    float* pof = outf ? outf + (size_t)row * D : nullptr;
    bf16* pob = outb ? outb + (size_t)row * D : nullptr;
    #pragma unroll
    for (int u = 0; u < 8; ++u) {
        int j = threadIdx.x + u * 256;
        float y = (v[u] - mean) * rstd;
        if (pof) pof[j] = y;
        if (pob) pob[j] = __float2bfloat16(y);
    }
}

// ---------------- launch ----------------
// Workspace plan (proven budget: 232 MB, same as the R3 passing layout).
//   [  0, 16) xb        -> qr (after QKV)   -> outb (after attn)
//   [ 16, 48) Wq^T/Wk^T -> kr@16-32         -> W1t (after LN1) -> W2t (after FFN1)
//   [ 32, 40) Wv^T      (dead after QKV)
//   [ 40, 88) qkv       -> attn fp32 @40-72 (after rope/vtrans)
//   [ 72,104) (qkv tail + vt@88-104) -> outf fp32 (after attn)
//   [104,168) h (FFN1 out, bf16 [M][8192])
//   [168,232) p0|p1 (FFN2 split-K fp32 partials)
extern "C" void kernel_launch(void* const* d_in, const int* in_sizes, int n_in,
                              void* d_out, int out_size, void* d_ws, size_t ws_size,
                              hipStream_t stream) {
    const float* x  = (const float*)d_in[0];
    const float* Wq = (const float*)d_in[1];
    const float* Wk = (const float*)d_in[2];
    const float* Wv = (const float*)d_in[3];
    const float* W1 = (const float*)d_in[4];
    const float* b1 = (const float*)d_in[5];
    const float* W2 = (const float*)d_in[6];
    const float* b2 = (const float*)d_in[7];
    const float* sn = (const float*)d_in[8];
    const float* cs = (const float*)d_in[9];

    const int B = 2, S = 2048, D = 2048, H = 16, Dff = 8192;
    const int M = B * S;                       // 4096
    const int NQKV = 3 * D;                    // 6144
    char* ws = (char*)d_ws;
    const size_t MB = 1024 * 1024;

    const size_t o_xb   = 0;                   // bf16 [M][D], 16 MB
    const size_t o_Wqkv = 16 * MB;             // bf16 [6144][2048], 24 MB
    const size_t o_qkv  = 40 * MB;             // bf16 [M][6144], 48 MB
    const size_t o_qr   = 0;                   // bf16 16 MB (xb dead)
    const size_t o_kr   = 16 * MB;             // bf16 16 MB (Wq^T/Wk^T dead)
    const size_t o_vt   = 88 * MB;             // bf16 [BH][128][S], 16 MB
    const size_t o_attn = 40 * MB;             // fp32 [M][D], 32 MB (qkv dead)
    const size_t o_outb = 0;                   // bf16 16 MB (qr dead)
    const size_t o_outf = 72 * MB;             // fp32 32 MB (qkv tail + vt dead)
    const size_t o_W1t  = 16 * MB;             // bf16 [8192][2048], 32 MB (kr/attn dead)
    const size_t o_h    = 104 * MB;            // bf16 [M][8192], 64 MB
    const size_t o_W2t  = 16 * MB;             // bf16 [2048][8192], 32 MB (W1t dead)
    const size_t o_p    = 168 * MB;            // fp32 2x[M][D], 64 MB

    // 1. x -> bf16; Wq/Wk/Wv -> stacked transposed bf16 [6144][2048]
    long nx = (long)M * D;
    cvt_f32_bf16<<<nx / 2048, 256, 0, stream>>>(x, (bf16*)(ws + o_xb), nx);
    transpose_cvt<<<dim3(D / 32, D / 32), 256, 0, stream>>>(
        Wq, (bf16*)(ws + o_Wqkv), D, D);
    transpose_cvt<<<dim3(D / 32, D / 32), 256, 0, stream>>>(
        Wk, (bf16*)(ws + o_Wqkv) + (size_t)D * D, D, D);
    transpose_cvt<<<dim3(D / 32, D / 32), 256, 0, stream>>>(
        Wv, (bf16*)(ws + o_Wqkv) + 2 * (size_t)D * D, D, D);

    // 2. fused QKV projection: [M][2048] x [6144][2048]^T -> [M][6144]
    gemm_pipe<0, 1><<<dim3(M / 256, NQKV / 128), 512, 0, stream>>>(
        (bf16*)(ws + o_xb), (bf16*)(ws + o_Wqkv), ws + o_qkv, nullptr, nullptr,
        M, NQKV, D);

    // 3. RoPE + V transpose (strided reads from fused buffer)
    rope_kernel<<<M, 256, 0, stream>>>((bf16*)(ws + o_qkv), (bf16*)(ws + o_qr),
                                       sn, cs, S, D, NQKV);
    rope_kernel<<<M, 256, 0, stream>>>((bf16*)(ws + o_qkv) + D, (bf16*)(ws + o_kr),
                                       sn, cs, S, D, NQKV);
    vtrans_kernel<<<dim3(S / 32, 4, B * H), 256, 0, stream>>>(
        (bf16*)(ws + o_qkv) + 2 * D, (bf16*)(ws + o_vt), S, D, H, NQKV);

    // 4. causal flash attention -> fp32 [M][D]
    attn_kernel<<<dim3(B * H, S / 64), 256, 0, stream>>>(
        (bf16*)(ws + o_qr), (bf16*)(ws + o_kr), (bf16*)(ws + o_vt),
        (float*)(ws + o_attn), S, D, H);

    // 5. LN(attn + x) -> outf (fp32, residual for LN2) + outb (bf16, FFN1 input)
    ln_kernel<<<M, 256, 0, stream>>>((float*)(ws + o_attn), x, nullptr, nullptr,
                                     (float*)(ws + o_outf), (bf16*)(ws + o_outb), D);

    // 6. W1^T (late: reuses kr/attn regions), then FFN1: gelu(out@W1+b1) -> bf16 h
    transpose_cvt<<<dim3(Dff / 32, D / 32), 256, 0, stream>>>(
        W1, (bf16*)(ws + o_W1t), D, Dff);
    gemm_pipe<1, 1><<<dim3(M / 256, Dff / 128), 512, 0, stream>>>(
        (bf16*)(ws + o_outb), (bf16*)(ws + o_W1t), ws + o_h, b1, nullptr, M, Dff, D);

    // 7. W2^T (late: reuses W1t region), then FFN2 split-K=2 -> p0|p1 fp32
    transpose_cvt<<<dim3(D / 32, Dff / 32), 256, 0, stream>>>(
        W2, (bf16*)(ws + o_W2t), Dff, D);
    gemm_pipe<3, 2><<<dim3(M / 256, D / 128, 2), 512, 0, stream>>>(
        (bf16*)(ws + o_h), (bf16*)(ws + o_W2t), ws + o_p, nullptr, nullptr, M, D, Dff);

    // 8. LN2( p0 + p1 + outf + b2 ) -> d_out fp32
    ln_kernel<<<M, 256, 0, stream>>>((float*)(ws + o_p),
                                     (float*)(ws + o_p) + (size_t)M * D,
                                     (float*)(ws + o_outf), b2,
                                     (float*)d_out, nullptr, D);
}

// Round 3
// 781.453 us; speedup vs baseline: 1.2097x; 1.0671x over previous
//
#include <hip/hip_runtime.h>
#include <hip/hip_bf16.h>
#include <math.h>
#include <stdint.h>

using bf16 = __hip_bfloat16;
typedef __attribute__((ext_vector_type(4))) float f32x4;
typedef __attribute__((ext_vector_type(8))) short s16x8;

#define MFMA16(a, b, c) __builtin_amdgcn_mfma_f32_16x16x32_bf16(a, b, c, 0, 0, 0)

__device__ __forceinline__ void gload_lds16(const void* g, void* l) {
    __builtin_amdgcn_global_load_lds(
        (const __attribute__((address_space(1))) void*)g,
        (__attribute__((address_space(3))) void*)l, 16, 0, 0);
}

// ---------------- fp32 -> bf16 straight convert (8 elems/thread) ----------------
struct alignas(16) bf16x8s { bf16 v[8]; };

__global__ void cvt_f32_bf16(const float* __restrict__ in, bf16* __restrict__ out, long n) {
    long i = ((long)blockIdx.x * 256 + threadIdx.x) * 8;
    if (i >= n) return;
    float4 a = *(const float4*)(in + i);
    float4 b = *(const float4*)(in + i + 4);
    bf16x8s r;
    r.v[0] = __float2bfloat16(a.x); r.v[1] = __float2bfloat16(a.y);
    r.v[2] = __float2bfloat16(a.z); r.v[3] = __float2bfloat16(a.w);
    r.v[4] = __float2bfloat16(b.x); r.v[5] = __float2bfloat16(b.y);
    r.v[6] = __float2bfloat16(b.z); r.v[7] = __float2bfloat16(b.w);
    *(bf16x8s*)(out + i) = r;
}

// ---------------- fp32 [K][N] -> bf16 [N][K] transpose-convert ----------------
__global__ void transpose_cvt(const float* __restrict__ W, bf16* __restrict__ Wt, int K, int N) {
    __shared__ bf16 t[32][33];
    int tx = threadIdx.x & 31, ty = threadIdx.x >> 5;
    int n0 = blockIdx.x * 32, k0 = blockIdx.y * 32;
    #pragma unroll
    for (int r = ty; r < 32; r += 8)
        t[r][tx] = __float2bfloat16(W[(size_t)(k0 + r) * N + n0 + tx]);
    __syncthreads();
    #pragma unroll
    for (int r = ty; r < 32; r += 8)
        Wt[(size_t)(n0 + r) * K + k0 + tx] = t[tx][r];
}

// ---------------- 256x256 ring-2 deep-pipelined GEMM, 4 quadrant-phases ---------
// C[M,N] = A[M,K] * Bt[N,K]^T, bf16 in, fp32 acc.
// 512 thr = 8 waves (2M x 4N), per-wave 128x64 output, BK=64.
// LDS = 2 slots x (A 32KB + B 32KB) = 128 KiB. 16B-block XOR swizzle
// (block ^= row&7), written via pre-swizzled GLOBAL source + LINEAR
// global_load_lds dest, read with same XOR.
// Tile is staged as 4 phase-aligned half-regions:
//   AH(h): rows {h*64..h*64+63} u {128+h*64..128+h*64+63}  (quarter-stacked)
//   BH(h): rows {wn*64 + h*32 .. +31} for wn=0..3
// Phase order (mtH,ntH) = (0,0),(1,0),(1,1),(0,1): region first needed:
//   AH0,BH0 @P0; AH1 @P1; BH1 @P2. Issue for tile t+1: A0B0@P0, A1@P1, B1@P2.
// Counted waits: vmcnt(6) before P1, vmcnt(6) before P2, vmcnt(4) at boundary.
// 3 barriers / 64 wave-MFMA per K-tile; never drains until the peeled last tile.
// EPI 0: bf16 store. EPI 1: bias+gelu -> bf16. EPI 3: fp32 split-K partial.
// REQUIRES: M%256==0, N%256==0, (K/SPLITK)%64==0, K/SPLITK>=128,
//           gridDim.x*gridDim.y % 8 == 0.
#define GEMM_LDS 131072

template <int EPI, int SPLITK>
__global__ __launch_bounds__(512) void gemm_pipe(
    const bf16* __restrict__ A, const bf16* __restrict__ Bt,
    void* __restrict__ C, const float* __restrict__ bias,
    const float* __restrict__ resid, int M, int N, int K)
{
    __shared__ __align__(16) char smem[GEMM_LDS];
    const int tid = threadIdx.x;
    const int wid = tid >> 6, lane = tid & 63;
    const int quad = lane >> 4, l16 = lane & 15;
    const int wm = wid >> 2, wn = wid & 3;

    // XCD-aware bijective block swizzle (nwg % 8 == 0 guaranteed by launcher)
    const int nx = gridDim.x;
    const int nwg = nx * gridDim.y;
    int lin = blockIdx.y * nx + blockIdx.x;
    const int cpx = nwg >> 3;
    lin = (lin & 7) * cpx + (lin >> 3);
    const int bm = (lin % nx) * 256, bn = (lin / nx) * 256;

    const int KH = K / SPLITK;
    const int kbeg = blockIdx.z * KH;
    const int NT = KH / 64;

    // ---- staging addresses (pre-swizzled global source) ----
    // thread's 16B chunk j (j=0,1): LDS region-local row r = (tid>>3)+64j,
    // 16B-block pb = tid&7; global col block = pb ^ (r&7) (r&7 j-invariant).
    const int r0 = tid >> 3, pb = tid & 7;
    const int gcol = ((pb ^ (r0 & 7)) << 3);
    const bf16* pA[2][2];
    const bf16* pB[2][2];
    #pragma unroll
    for (int h = 0; h < 2; ++h)
        #pragma unroll
        for (int j = 0; j < 2; ++j) {
            pA[h][j] = A + (size_t)(bm + h * 64 + j * 128 + r0) * K + kbeg + gcol;
            pB[h][j] = Bt + (size_t)(bn + ((r0 >> 5) + 2 * j) * 64 + h * 32 + (r0 & 31)) * K
                       + kbeg + gcol;
        }
    // LDS byte dests (add slot*65536): A regions at 0/16384, B at 32768/49152
    const int dA0 = tid * 16;
    const int dA1 = 16384 + tid * 16;
    const int dB0 = 32768 + tid * 16;
    const int dB1 = 49152 + tid * 16;

#define ST_A(h, base, T1) { \
    gload_lds16(pA[h][0] + (T1) * 64, smem + (base)); \
    gload_lds16(pA[h][1] + (T1) * 64, smem + (base) + 8192); }
#define ST_B(h, base, T1) { \
    gload_lds16(pB[h][0] + (T1) * 64, smem + (base)); \
    gload_lds16(pB[h][1] + (T1) * 64, smem + (base) + 8192); }

    // ---- fragment read offsets (bf16 elems within slot) ----
    const int asw = l16 & 7;
    const int kx0 = (quad ^ asw) << 3;
    const int kx1 = ((4 + quad) ^ asw) << 3;
    const int aq0 = wm * 4096 + l16 * 64;          // A quarter (mtH0, wm)
    const int aq1 = (2 + wm) * 4096 + l16 * 64;    // A quarter (mtH1, wm)
    const int bq0 = 16384 + wn * 2048 + l16 * 64;  // B region ntH0
    const int bq1 = bq0 + 8192;                    // B region ntH1

#define LDA(base) { _Pragma("unroll") for (int mt = 0; mt < 4; ++mt) { \
    aF[0][mt] = *(const s16x8*)(sa + (base) + mt * 1024 + kx0); \
    aF[1][mt] = *(const s16x8*)(sa + (base) + mt * 1024 + kx1); } }
#define LDB(base) { _Pragma("unroll") for (int nt = 0; nt < 2; ++nt) { \
    bF[0][nt] = *(const s16x8*)(sa + (base) + nt * 1024 + kx0); \
    bF[1][nt] = *(const s16x8*)(sa + (base) + nt * 1024 + kx1); } }
#define MM(mo, no) { \
    __builtin_amdgcn_s_setprio(1); \
    _Pragma("unroll") for (int kh = 0; kh < 2; ++kh) \
    _Pragma("unroll") for (int mt = 0; mt < 4; ++mt) \
    _Pragma("unroll") for (int nt = 0; nt < 2; ++nt) \
        acc[(mo) + mt][(no) + nt] = MFMA16(aF[kh][mt], bF[kh][nt], acc[(mo) + mt][(no) + nt]); \
    __builtin_amdgcn_s_setprio(0); }

    f32x4 acc[8][4] = {};
    s16x8 aF[2][4], bF[2][2];

    // prologue: stage tile 0 into slot 0 (issue order: A0,B0,A1,B1)
    ST_A(0, dA0, 0); ST_B(0, dB0, 0);
    ST_A(1, dA1, 0);
    ST_B(1, dB1, 0);
    asm volatile("s_waitcnt vmcnt(4)" ::: "memory");
    __builtin_amdgcn_s_barrier();

    for (int t = 0; t < NT - 1; ++t) {
        const int sl = t & 1;
        const bf16* sa = (const bf16*)smem + sl * 32768;
        const int sb1 = (sl ^ 1) * 65536;
        // P0: quadrant (mtH0, ntH0); stage A0,B0 of t+1
        LDA(aq0); LDB(bq0);
        ST_A(0, sb1 + dA0, t + 1); ST_B(0, sb1 + dB0, t + 1);
        MM(0, 0);
        asm volatile("s_waitcnt vmcnt(6)" ::: "memory");   // retire A1(t)
        __builtin_amdgcn_s_barrier();
        // P1: (mtH1, ntH0); B frags reused; stage A1 of t+1
        LDA(aq1);
        ST_A(1, sb1 + dA1, t + 1);
        MM(4, 0);
        asm volatile("s_waitcnt vmcnt(6)" ::: "memory");   // retire B1(t)
        __builtin_amdgcn_s_barrier();
        // P2: (mtH1, ntH1); A frags reused; stage B1 of t+1
        LDB(bq1);
        ST_B(1, sb1 + dB1, t + 1);
        MM(4, 2);
        // P3: (mtH0, ntH1); B frags reused; re-read A0 (region still valid)
        LDA(aq0);
        MM(0, 2);
        asm volatile("s_waitcnt vmcnt(4)" ::: "memory");   // retire A0,B0(t+1)
        __builtin_amdgcn_s_barrier();
    }
    {   // final tile: no staging; tail waits drain the remaining 4 loads
        const bf16* sa = (const bf16*)smem + ((NT - 1) & 1) * 32768;
        LDA(aq0); LDB(bq0);
        MM(0, 0);
        asm volatile("s_waitcnt vmcnt(2)" ::: "memory");   // retire A1(last)
        __builtin_amdgcn_s_barrier();
        LDA(aq1);
        MM(4, 0);
        asm volatile("s_waitcnt vmcnt(0)" ::: "memory");   // retire B1(last)
        __builtin_amdgcn_s_barrier();
        LDB(bq1);
        MM(4, 2);
        LDA(aq0);
        MM(0, 2);
    }
#undef ST_A
#undef ST_B
#undef LDA
#undef LDB
#undef MM

    float* Cp = (float*)C;
    if (EPI == 3) Cp += (size_t)blockIdx.z * M * N;

    #pragma unroll
    for (int m = 0; m < 8; ++m) {
        #pragma unroll
        for (int n = 0; n < 4; ++n) {
            #pragma unroll
            for (int r = 0; r < 4; ++r) {
                int row = bm + wm * 128 + m * 16 + quad * 4 + r;
                int col = bn + wn * 64 + n * 16 + l16;
                float v = acc[m][n][r];
                if (EPI == 0) {
                    ((bf16*)C)[(size_t)row * N + col] = __float2bfloat16(v);
                } else if (EPI == 1) {
                    float xx = v + bias[col];
                    float g = 0.5f * xx * (1.0f + erff(xx * 0.7071067811865475f));
                    ((bf16*)C)[(size_t)row * N + col] = __float2bfloat16(g);
                } else if (EPI == 2) {
                    ((float*)C)[(size_t)row * N + col] =
                        v + bias[col] + resid[(size_t)row * N + col];
                } else {
                    Cp[(size_t)row * N + col] = v;
                }
            }
        }
    }
}

// ---------------- RoPE (reference indexes sin/cos by BATCH, not position) --------
__global__ void rope_kernel(const bf16* __restrict__ in, bf16* __restrict__ out,
                            const float* __restrict__ sn, const float* __restrict__ cs,
                            int S, int D, int instride) {
    int row = blockIdx.x;
    int pos = row / S;                 // batch index — matches reference broadcast
    const int half = D >> 1;
    const bf16* r = in + (size_t)row * instride;
    bf16* o = out + (size_t)row * D;
    for (int j = threadIdx.x; j < half; j += 256) {
        uint32_t pr = *(const uint32_t*)(r + 2 * j);
        float x1 = __uint_as_float(pr << 16);
        float x2 = __uint_as_float(pr & 0xffff0000u);
        float c = cs[(size_t)pos * half + j], s = sn[(size_t)pos * half + j];
        o[j]        = __float2bfloat16(x1 * c - x2 * s);
        o[half + j] = __float2bfloat16(x1 * s + x2 * c);
    }
}

// ---------------- V transpose per head: v[b,s,h,d] (strided) -> vt[bh, d, s] -----
__global__ void vtrans_kernel(const bf16* __restrict__ v, bf16* __restrict__ vt,
                              int S, int D, int H, int instride) {
    __shared__ bf16 t[32][33];
    int bh = blockIdx.z, b = bh >> 4, h = bh & 15;
    int s0 = blockIdx.x * 32, d0 = blockIdx.y * 32;
    int tx = threadIdx.x & 31, ty = threadIdx.x >> 5;
    #pragma unroll
    for (int r = ty; r < 32; r += 8)
        t[r][tx] = v[(size_t)(b * S + s0 + r) * instride + h * 128 + d0 + tx];
    __syncthreads();
    #pragma unroll
    for (int r = ty; r < 32; r += 8)
        vt[((size_t)bh * 128 + d0 + r) * S + s0 + tx] = t[tx][r];
}

// ---------------- Flash attention, transposed-score form ----------------
__global__ __launch_bounds__(256, 4) void attn_kernel(
    const bf16* __restrict__ q, const bf16* __restrict__ k, const bf16* __restrict__ vt,
    float* __restrict__ o, int S, int D, int H)
{
    __shared__ __align__(16) char smem[40960];
    bf16* Ks = (bf16*)smem;                 // [64 k][128 d], 16B-block XOR swizzle
    bf16* Vs = (bf16*)(smem + 16384);       // [128 d][64 k], swizzled
    bf16* Ps = (bf16*)(smem + 32768);       // per-wave [16 q][64 k], swizzled

    const int tid = threadIdx.x, wid = tid >> 6, lane = tid & 63;
    const int quad = lane >> 4, l16 = lane & 15;
    const int bh = blockIdx.x, b = bh >> 4, h = bh & 15;
    const int qt = gridDim.y - 1 - blockIdx.y;     // big tiles dispatched first
    const float scale = 0.08838834764831845f;      // 1/sqrt(128)

    s16x8 qf[4];
    const bf16* qrow = q + ((size_t)(b * S + qt * 64 + wid * 16 + l16)) * D + h * 128;
    #pragma unroll
    for (int ks = 0; ks < 4; ++ks)
        qf[ks] = *(const s16x8*)(qrow + ks * 32 + quad * 8);

    f32x4 oacc[8] = {};
    float mstate = -INFINITY, lstate = 0.f;

    const bf16* kb0 = k + (size_t)(b * S) * D + h * 128;
    const bf16* vb0 = vt + (size_t)bh * 128 * S;
    bf16* psw = Ps + wid * 16 * 64;
    const int sw = l16 & 7;
    const int nch = qt + 1;

    for (int kc = 0; kc < nch; ++kc) {
        __syncthreads();
        #pragma unroll
        for (int c = 0; c < 4; ++c) {
            int choff = (wid * 4 + c) << 10;
            int off = choff + lane * 16;
            int rk = off >> 8, bk = (off & 255) >> 4;
            gload_lds16(kb0 + (size_t)(kc * 64 + rk) * D + ((bk ^ (rk & 7)) << 3),
                        (char*)Ks + choff);
            int rv = off >> 7, bv = (off & 127) >> 4;
            gload_lds16(vb0 + (size_t)rv * S + kc * 64 + ((bv ^ (rv & 7)) << 3),
                        (char*)Vs + choff);
        }
        __syncthreads();

        f32x4 sacc[4] = {};
        #pragma unroll
        for (int mt = 0; mt < 4; ++mt) {
            #pragma unroll
            for (int ks = 0; ks < 4; ++ks) {
                s16x8 kf = *(const s16x8*)(Ks + (mt * 16 + l16) * 128 +
                                           (((ks * 4 + quad) ^ sw) << 3));
                sacc[mt] = MFMA16(kf, qf[ks], sacc[mt]);
            }
        }

        const bool need_mask = (kc == qt);
        #pragma unroll
        for (int mt = 0; mt < 4; ++mt)
            #pragma unroll
            for (int r = 0; r < 4; ++r) {
                float vv = sacc[mt][r] * scale;
                if (need_mask) {
                    int kl = mt * 16 + quad * 4 + r;
                    if (kl > wid * 16 + l16) vv = -INFINITY;
                }
                sacc[mt][r] = vv;
            }

        float mx = fmaxf(fmaxf(fmaxf(sacc[0][0], sacc[0][1]), fmaxf(sacc[0][2], sacc[0][3])),
                         fmaxf(fmaxf(sacc[1][0], sacc[1][1]), fmaxf(sacc[1][2], sacc[1][3])));
        mx = fmaxf(mx, fmaxf(fmaxf(fmaxf(sacc[2][0], sacc[2][1]), fmaxf(sacc[2][2], sacc[2][3])),
                             fmaxf(fmaxf(sacc[3][0], sacc[3][1]), fmaxf(sacc[3][2], sacc[3][3]))));
        mx = fmaxf(mx, __shfl_xor(mx, 16, 64));
        mx = fmaxf(mx, __shfl_xor(mx, 32, 64));
        float mnew = fmaxf(mstate, mx);
        float alpha = __expf(mstate - mnew);
        float rs = 0.f;
        #pragma unroll
        for (int mt = 0; mt < 4; ++mt)
            #pragma unroll
            for (int r = 0; r < 4; ++r) {
                float p = __expf(sacc[mt][r] - mnew);
                sacc[mt][r] = p;
                rs += p;
            }
        rs += __shfl_xor(rs, 16, 64);
        rs += __shfl_xor(rs, 32, 64);
        lstate = lstate * alpha + rs;
        mstate = mnew;
        #pragma unroll
        for (int mt = 0; mt < 8; ++mt)
            #pragma unroll
            for (int r = 0; r < 4; ++r) oacc[mt][r] *= alpha;

        #pragma unroll
        for (int mt = 0; mt < 4; ++mt)
            #pragma unroll
            for (int r = 0; r < 4; ++r) {
                int kl = mt * 16 + quad * 4 + r;
                psw[l16 * 64 + (((kl >> 3) ^ sw) << 3) + (kl & 7)] =
                    __float2bfloat16(sacc[mt][r]);
            }

        #pragma unroll
        for (int ks2 = 0; ks2 < 2; ++ks2) {
            s16x8 pf = *(const s16x8*)(psw + l16 * 64 + (((ks2 * 4 + quad) ^ sw) << 3));
            #pragma unroll
            for (int mt = 0; mt < 8; ++mt) {
                s16x8 vf = *(const s16x8*)(Vs + (mt * 16 + l16) * 64 +
                                           (((ks2 * 4 + quad) ^ sw) << 3));
                oacc[mt] = MFMA16(vf, pf, oacc[mt]);
            }
        }
    }

    float inv = 1.0f / lstate;
    __syncthreads();
    float* osw = (float*)smem + wid * 16 * 130;
    #pragma unroll
    for (int mt = 0; mt < 8; ++mt)
        #pragma unroll
        for (int r = 0; r < 4; ++r)
            osw[l16 * 130 + mt * 16 + quad * 4 + r] = oacc[mt][r] * inv;
    float* obase = o + (size_t)(b * S + qt * 64 + wid * 16) * D + h * 128;
    #pragma unroll
    for (int r16 = 0; r16 < 16; ++r16) {
        float2 val = *(const float2*)(osw + r16 * 130 + lane * 2);
        *(float2*)(obase + (size_t)r16 * D + lane * 2) = val;
    }
}

// ---------------- LayerNorm over D=2048: x = a (+b) (+c) (+bias), dual out ------
__global__ __launch_bounds__(256) void ln_kernel(
    const float* __restrict__ a, const float* __restrict__ b,
    const float* __restrict__ c, const float* __restrict__ bias,
    float* __restrict__ outf, bf16* __restrict__ outb, int D)
{
    int row = blockIdx.x;
    const float* pa = a + (size_t)row * D;
    const float* pb = b ? b + (size_t)row * D : nullptr;
    const float* pc = c ? c + (size_t)row * D : nullptr;
    float v[8];
    float sum = 0.f, sq = 0.f;
    #pragma unroll
    for (int u = 0; u < 8; ++u) {
        int j = threadIdx.x + u * 256;
        float x = pa[j];
        if (pb) x += pb[j];
        if (pc) x += pc[j];
        if (bias) x += bias[j];
        v[u] = x; sum += x; sq += x * x;
    }
    #pragma unroll
    for (int off = 32; off > 0; off >>= 1) {
        sum += __shfl_down(sum, off, 64);
        sq  += __shfl_down(sq,  off, 64);
    }
    __shared__ float red[8];
    int wid = threadIdx.x >> 6, lane = threadIdx.x & 63;
    if (lane == 0) { red[wid] = sum; red[4 + wid] = sq; }
    __syncthreads();
    sum = red[0] + red[1] + red[2] + red[3];
    sq  = red[4] + red[5] + red[6] + red[7];
    float mean = sum / D;
    float var = sq / D - mean * mean;
    float rstd = rsqrtf(fmaxf(var, 0.f) + 1e-5f);
    float* pof = outf ? outf + (size_t)row * D : nullptr;
    bf16* pob = outb ? outb + (size_t)row * D : nullptr;
    #pragma unroll
    for (int u = 0; u < 8; ++u) {
        int j = threadIdx.x + u * 256;
        float y = (v[u] - mean) * rstd;
        if (pof) pof[j] = y;
        if (pob) pob[j] = __float2bfloat16(y);
    }
}

// ---------------- launch ----------------
// Workspace plan (proven budget: 232 MB).
//   [  0, 16) xb        -> qr (after QKV)   -> outb (after attn)
//   [ 16, 48) Wq^T/Wk^T -> kr@16-32         -> W1t (after LN1) -> W2t (after FFN1)
//   [ 32, 40) Wv^T      (dead after QKV)
//   [ 40, 88) qkv       -> attn fp32 @40-72 (after rope/vtrans)
//   [ 72,104) (qkv tail + vt@88-104) -> outf fp32 (after attn)
//   [104,168) h (FFN1 out, bf16 [M][8192])
//   [168,232) p0|p1 (FFN2 split-K fp32 partials)
extern "C" void kernel_launch(void* const* d_in, const int* in_sizes, int n_in,
                              void* d_out, int out_size, void* d_ws, size_t ws_size,
                              hipStream_t stream) {
    const float* x  = (const float*)d_in[0];
    const float* Wq = (const float*)d_in[1];
    const float* Wk = (const float*)d_in[2];
    const float* Wv = (const float*)d_in[3];
    const float* W1 = (const float*)d_in[4];
    const float* b1 = (const float*)d_in[5];
    const float* W2 = (const float*)d_in[6];
    const float* b2 = (const float*)d_in[7];
    const float* sn = (const float*)d_in[8];
    const float* cs = (const float*)d_in[9];

    const int B = 2, S = 2048, D = 2048, H = 16, Dff = 8192;
    const int M = B * S;                       // 4096
    const int NQKV = 3 * D;                    // 6144
    char* ws = (char*)d_ws;
    const size_t MB = 1024 * 1024;

    const size_t o_xb   = 0;                   // bf16 [M][D], 16 MB
    const size_t o_Wqkv = 16 * MB;             // bf16 [6144][2048], 24 MB
    const size_t o_qkv  = 40 * MB;             // bf16 [M][6144], 48 MB
    const size_t o_qr   = 0;                   // bf16 16 MB (xb dead)
    const size_t o_kr   = 16 * MB;             // bf16 16 MB (Wq^T/Wk^T dead)
    const size_t o_vt   = 88 * MB;             // bf16 [BH][128][S], 16 MB
    const size_t o_attn = 40 * MB;             // fp32 [M][D], 32 MB (qkv dead)
    const size_t o_outb = 0;                   // bf16 16 MB (qr dead)
    const size_t o_outf = 72 * MB;             // fp32 32 MB (qkv tail + vt dead)
    const size_t o_W1t  = 16 * MB;             // bf16 [8192][2048], 32 MB (kr/attn dead)
    const size_t o_h    = 104 * MB;            // bf16 [M][8192], 64 MB
    const size_t o_W2t  = 16 * MB;             // bf16 [2048][8192], 32 MB (W1t dead)
    const size_t o_p    = 168 * MB;            // fp32 2x[M][D], 64 MB

    // 1. x -> bf16; Wq/Wk/Wv -> stacked transposed bf16 [6144][2048]
    long nx = (long)M * D;
    cvt_f32_bf16<<<nx / 2048, 256, 0, stream>>>(x, (bf16*)(ws + o_xb), nx);
    transpose_cvt<<<dim3(D / 32, D / 32), 256, 0, stream>>>(
        Wq, (bf16*)(ws + o_Wqkv), D, D);
    transpose_cvt<<<dim3(D / 32, D / 32), 256, 0, stream>>>(
        Wk, (bf16*)(ws + o_Wqkv) + (size_t)D * D, D, D);
    transpose_cvt<<<dim3(D / 32, D / 32), 256, 0, stream>>>(
        Wv, (bf16*)(ws + o_Wqkv) + 2 * (size_t)D * D, D, D);

    // 2. fused QKV projection: [M][2048] x [6144][2048]^T -> [M][6144]
    gemm_pipe<0, 1><<<dim3(M / 256, NQKV / 256), 512, 0, stream>>>(
        (bf16*)(ws + o_xb), (bf16*)(ws + o_Wqkv), ws + o_qkv, nullptr, nullptr,
        M, NQKV, D);

    // 3. RoPE + V transpose (strided reads from fused buffer)
    rope_kernel<<<M, 256, 0, stream>>>((bf16*)(ws + o_qkv), (bf16*)(ws + o_qr),
                                       sn, cs, S, D, NQKV);
    rope_kernel<<<M, 256, 0, stream>>>((bf16*)(ws + o_qkv) + D, (bf16*)(ws + o_kr),
                                       sn, cs, S, D, NQKV);
    vtrans_kernel<<<dim3(S / 32, 4, B * H), 256, 0, stream>>>(
        (bf16*)(ws + o_qkv) + 2 * D, (bf16*)(ws + o_vt), S, D, H, NQKV);

    // 4. causal flash attention -> fp32 [M][D]
    attn_kernel<<<dim3(B * H, S / 64), 256, 0, stream>>>(
        (bf16*)(ws + o_qr), (bf16*)(ws + o_kr), (bf16*)(ws + o_vt),
        (float*)(ws + o_attn), S, D, H);

    // 5. LN(attn + x) -> outf (fp32, residual for LN2) + outb (bf16, FFN1 input)
    ln_kernel<<<M, 256, 0, stream>>>((float*)(ws + o_attn), x, nullptr, nullptr,
                                     (float*)(ws + o_outf), (bf16*)(ws + o_outb), D);

    // 6. W1^T (late: reuses kr/attn regions), then FFN1: gelu(out@W1+b1) -> bf16 h
    transpose_cvt<<<dim3(Dff / 32, D / 32), 256, 0, stream>>>(
        W1, (bf16*)(ws + o_W1t), D, Dff);
    gemm_pipe<1, 1><<<dim3(M / 256, Dff / 256), 512, 0, stream>>>(
        (bf16*)(ws + o_outb), (bf16*)(ws + o_W1t), ws + o_h, b1, nullptr, M, Dff, D);

    // 7. W2^T (late: reuses W1t region), then FFN2 split-K=2 -> p0|p1 fp32
    transpose_cvt<<<dim3(D / 32, Dff / 32), 256, 0, stream>>>(
        W2, (bf16*)(ws + o_W2t), Dff, D);
    gemm_pipe<3, 2><<<dim3(M / 256, D / 256, 2), 512, 0, stream>>>(
        (bf16*)(ws + o_h), (bf16*)(ws + o_W2t), ws + o_p, nullptr, nullptr, M, D, Dff);

    // 8. LN2( p0 + p1 + outf + b2 ) -> d_out fp32
    ln_kernel<<<M, 256, 0, stream>>>((float*)(ws + o_p),
                                     (float*)(ws + o_p) + (size_t)M * D,
                                     (float*)(ws + o_outf), b2,
                                     (float*)d_out, nullptr, D);
}